// Round 14
// baseline (213.114 us; speedup 1.0000x reference)
//
#include <hip/hip_runtime.h>
#include <math.h>

#define NN 100000
#define EE 400000
#define GG 4096
#define INF_ 27
#define CC 128   // H*D
#define HH 4
#define DD 32
#define NB 98    // ceil(NN/1024) scan blocks

typedef short bf16x8 __attribute__((ext_vector_type(8)));
typedef float f32x4 __attribute__((ext_vector_type(4)));

// ---- bf16 helpers (RNE) ----
static __device__ __forceinline__ unsigned short f2bf(float f){
  unsigned u = __float_as_uint(f);
  u += 0x7fffu + ((u>>16)&1u);
  return (unsigned short)(u>>16);
}
static __device__ __forceinline__ float bf2f(unsigned short s){
  return __uint_as_float(((unsigned)s)<<16);
}

// ---- fused prep: zero deg, graph boundaries, x->bf16(pad32), w1/res1/w2->bf16 ----
__global__ __launch_bounds__(256) void k_prep(
    const float* __restrict__ x, const float* __restrict__ fcw,
    const float* __restrict__ resw, const float* __restrict__ w2,
    const int* __restrict__ gid,
    unsigned short* __restrict__ xb, unsigned short* __restrict__ wb1,
    unsigned short* __restrict__ wrb, unsigned short* __restrict__ wb2,
    int* __restrict__ deg, int* __restrict__ gptr)
{
  int i = blockIdx.x*256 + threadIdx.x;
  if (i < NN*32){
    int n = i>>5, k = i&31;
    xb[i] = (k<INF_) ? f2bf(x[n*INF_+k]) : (unsigned short)0;
  }
  if (i < NN){
    deg[i] = 0;
    int g = gid[i];
    int gp = (i==0) ? -1 : gid[i-1];
    for (int q=gp+1; q<=g; q++) gptr[q] = i;
    if (i==NN-1){
      for (int q=g+1; q<=GG; q++) gptr[q] = NN;
    }
  }
  if (i < CC*CC) wb2[i] = f2bf(w2[i]);
  if (i < CC*32){
    int c = i>>5, k = i&31;
    wb1[i] = (k<INF_) ? f2bf(fcw[c*INF_+k]) : (unsigned short)0;
    wrb[i] = (k<INF_) ? f2bf(resw[c*INF_+k]) : (unsigned short)0;
  }
}

__global__ void k_count(const int* __restrict__ dst, int* __restrict__ deg){
  int i = blockIdx.x*blockDim.x + threadIdx.x;
  if (i < EE) atomicAdd(&deg[dst[i]], 1);
}

__global__ __launch_bounds__(256) void k_scan_local(const int* __restrict__ deg,
                                                    int* __restrict__ rowptr,
                                                    int* __restrict__ bsum){
  __shared__ int sh[256];
  int t = threadIdx.x;
  int idx = blockIdx.x*1024 + t*4;
  int v0 = (idx+0<NN)?deg[idx+0]:0;
  int v1 = (idx+1<NN)?deg[idx+1]:0;
  int v2 = (idx+2<NN)?deg[idx+2]:0;
  int v3 = (idx+3<NN)?deg[idx+3]:0;
  sh[t] = v0+v1+v2+v3;
  __syncthreads();
  for (int o=1;o<256;o<<=1){
    int x = (t>=o)? sh[t-o] : 0;
    __syncthreads();
    sh[t] += x;
    __syncthreads();
  }
  int run = (t==0)? 0 : sh[t-1];
  if (t==255) bsum[blockIdx.x] = sh[255];
  if (idx+0<NN){ rowptr[idx+0]=run; run+=v0; }
  if (idx+1<NN){ rowptr[idx+1]=run; run+=v1; }
  if (idx+2<NN){ rowptr[idx+2]=run; run+=v2; }
  if (idx+3<NN){ rowptr[idx+3]=run; }
}

__global__ void k_scan_bsums(int* __restrict__ bsum, int* __restrict__ rowptr){
  if (threadIdx.x==0 && blockIdx.x==0){
    int run = 0;
    for (int b=0;b<NB;b++){ int v=bsum[b]; bsum[b]=run; run+=v; }
    rowptr[NN] = run;
  }
}

__global__ __launch_bounds__(256) void k_scan_add(int* __restrict__ rowptr,
                                                  const int* __restrict__ bsum,
                                                  int* __restrict__ cursor){
  int idx = blockIdx.x*1024 + threadIdx.x*4;
  int off = bsum[blockIdx.x];
  #pragma unroll
  for (int i=0;i<4;i++){
    if (idx+i<NN){ int r = rowptr[idx+i]+off; rowptr[idx+i]=r; cursor[idx+i]=r; }
  }
}

__global__ void k_scatter(const int* __restrict__ src, const int* __restrict__ dst,
                          int* __restrict__ cursor, int* __restrict__ csr_src,
                          int* __restrict__ csr_dst){
  int i = blockIdx.x*blockDim.x + threadIdx.x;
  if (i < EE){
    int d = dst[i];
    int pos = atomicAdd(&cursor[d], 1);
    csr_src[pos] = src[i];
    csr_dst[pos] = d;
  }
}

// ---- per-edge attention weights in CSR order (fully parallel, breaks the
//      dependent-gather chain in the aggr kernels) ----
__global__ __launch_bounds__(256) void k_alpha(
    const int* __restrict__ csr_src, const int* __restrict__ csr_dst,
    const float* __restrict__ el, const float* __restrict__ er,
    float4* __restrict__ alpha)
{
  int j = blockIdx.x*256 + threadIdx.x;
  if (j >= EE) return;
  int s = csr_src[j], d = csr_dst[j];
  float4 a = *(const float4*)(el + s*HH);
  float4 b = *(const float4*)(er + d*HH);
  float4 o;
  float v;
  v = a.x + b.x; v = v>0.f?v:0.2f*v; o.x = __expf(v);
  v = a.y + b.y; v = v>0.f?v:0.2f*v; o.y = __expf(v);
  v = a.z + b.z; v = v>0.f?v:0.2f*v; o.z = __expf(v);
  v = a.w + b.w; v = v>0.f?v:0.2f*v; o.w = __expf(v);
  alpha[j] = o;
}

// ---- layer1 via MFMA: featb = bf16(x@fc1^T), resb = bf16(x@res1^T + b1), el/er ----
__global__ __launch_bounds__(256) void k_feat1m(
    const unsigned short* __restrict__ xb, const unsigned short* __restrict__ wb1,
    const unsigned short* __restrict__ wrb, const float* __restrict__ bias,
    const float* __restrict__ al, const float* __restrict__ ar,
    unsigned short* __restrict__ featb, unsigned short* __restrict__ resb,
    float* __restrict__ el, float* __restrict__ er)
{
  int wid = (blockIdx.x*256 + threadIdx.x) >> 6;
  int lane = threadIdx.x & 63;
  int l15 = lane & 15, khi = lane >> 4;
  int nw = gridDim.x*4;
  bf16x8 wf[8], wr[8];
  float bv8[8];
  #pragma unroll
  for (int ct=0; ct<8; ct++){
    wf[ct] = *(const bf16x8*)(wb1 + (ct*16+l15)*32 + khi*8);
    wr[ct] = *(const bf16x8*)(wrb + (ct*16+l15)*32 + khi*8);
    bv8[ct] = bias[ct*16+l15];
  }
  float a0v[4], a1v[4], b0v[4], b1v[4];
  #pragma unroll
  for (int hh=0; hh<4; hh++){
    int c0 = hh*32 + l15;
    a0v[hh] = al[c0]; a1v[hh] = al[c0+16];
    b0v[hh] = ar[c0]; b1v[hh] = ar[c0+16];
  }
  for (int tile = wid; tile < NN/16; tile += nw){
    int n0 = tile*16;
    bf16x8 af = *(const bf16x8*)(xb + (size_t)(n0+l15)*32 + khi*8);
    f32x4 accf[8], accr[8];
    #pragma unroll
    for (int ct=0; ct<8; ct++){
      accf[ct] = __builtin_amdgcn_mfma_f32_16x16x32_bf16(af, wf[ct], (f32x4){0.f,0.f,0.f,0.f}, 0,0,0);
      accr[ct] = __builtin_amdgcn_mfma_f32_16x16x32_bf16(af, wr[ct], (f32x4){0.f,0.f,0.f,0.f}, 0,0,0);
    }
    #pragma unroll
    for (int ct=0; ct<8; ct++){
      int c = ct*16+l15;
      #pragma unroll
      for (int r=0;r<4;r++){
        int n = n0 + khi*4 + r;
        featb[(size_t)n*CC + c] = f2bf(accf[ct][r]);
        resb [(size_t)n*CC + c] = f2bf(accr[ct][r] + bv8[ct]);
      }
    }
    #pragma unroll
    for (int hh=0; hh<4; hh++){
      #pragma unroll
      for (int r=0;r<4;r++){
        float pe = accf[2*hh][r]*a0v[hh] + accf[2*hh+1][r]*a1v[hh];
        float pr = accf[2*hh][r]*b0v[hh] + accf[2*hh+1][r]*b1v[hh];
        #pragma unroll
        for (int o=8;o;o>>=1){ pe += __shfl_xor(pe,o,16); pr += __shfl_xor(pr,o,16); }
        if (l15==0){
          int n = n0 + khi*4 + r;
          el[n*HH + hh] = pe;
          er[n*HH + hh] = pr;
        }
      }
    }
  }
}

// ---- layer2 GEMM via MFMA: featb = bf16(hb @ fc2^T), el/er dots ----
__global__ __launch_bounds__(256) void k_feat2(
    const unsigned short* __restrict__ hb, const unsigned short* __restrict__ wb2,
    const float* __restrict__ al, const float* __restrict__ ar,
    unsigned short* __restrict__ featb, float* __restrict__ el, float* __restrict__ er)
{
  int wid = (blockIdx.x*256 + threadIdx.x) >> 6;
  int lane = threadIdx.x & 63;
  int tile = wid >> 1;
  int ch = wid & 1;
  if (tile >= NN/16) return;
  int l15 = lane & 15, khi = lane >> 4;
  int n0 = tile*16;
  bf16x8 wf[4][4];
  #pragma unroll
  for (int ct=0; ct<4; ct++)
    #pragma unroll
    for (int ks=0; ks<4; ks++)
      wf[ct][ks] = *(const bf16x8*)(wb2 + (size_t)(ch*64+ct*16+l15)*CC + ks*32 + khi*8);
  bf16x8 af[4];
  #pragma unroll
  for (int ks=0; ks<4; ks++)
    af[ks] = *(const bf16x8*)(hb + (size_t)(n0+l15)*CC + ks*32 + khi*8);
  f32x4 accf[4] = {{0.f,0.f,0.f,0.f},{0.f,0.f,0.f,0.f},{0.f,0.f,0.f,0.f},{0.f,0.f,0.f,0.f}};
  #pragma unroll
  for (int ks=0; ks<4; ks++)
    #pragma unroll
    for (int ct=0; ct<4; ct++)
      accf[ct] = __builtin_amdgcn_mfma_f32_16x16x32_bf16(af[ks], wf[ct][ks], accf[ct], 0,0,0);
  #pragma unroll
  for (int ct=0; ct<4; ct++)
    #pragma unroll
    for (int r=0;r<4;r++)
      featb[(size_t)(n0+khi*4+r)*CC + ch*64+ct*16+l15] = f2bf(accf[ct][r]);
  #pragma unroll
  for (int hh=0; hh<2; hh++){
    int c0 = ch*64 + hh*32 + l15;
    float a0 = al[c0], a1 = al[c0+16], b0 = ar[c0], b1 = ar[c0+16];
    #pragma unroll
    for (int r=0;r<4;r++){
      float pe = accf[2*hh][r]*a0 + accf[2*hh+1][r]*a1;
      float pr = accf[2*hh][r]*b0 + accf[2*hh+1][r]*b1;
      #pragma unroll
      for (int o=8;o;o>>=1){ pe += __shfl_xor(pe,o,16); pr += __shfl_xor(pr,o,16); }
      if (l15==0){
        int n = n0 + khi*4 + r;
        el[n*HH + ch*2+hh] = pe;
        er[n*HH + ch*2+hh] = pr;
      }
    }
  }
}

// ---- layer1 aggregation: 16 lanes/node, 8 ch/lane; alpha precomputed ----
__global__ __launch_bounds__(256) void k_aggr1(
    const int* __restrict__ rowptr, const int* __restrict__ csr,
    const float* __restrict__ alpha,
    const unsigned short* __restrict__ featb,
    const unsigned short* __restrict__ resb,
    unsigned short* __restrict__ hb)
{
  int t = threadIdx.x;
  int n = blockIdx.x*16 + (t>>4);
  if (n >= NN) return;
  int l = t & 15;
  int h = l >> 2;
  int e0 = rowptr[n], e1 = rowptr[n+1];
  float ssum = 0.f;
  float r[8] = {0.f,0.f,0.f,0.f,0.f,0.f,0.f,0.f};
  int j = e0;
  for (; j+2 <= e1; j += 2){
    int sA = csr[j], sB = csr[j+1];
    float aA = alpha[j*4 + h], aB = alpha[(j+1)*4 + h];
    ssum += aA + aB;
    bf16x8 fA = *(const bf16x8*)(featb + (size_t)sA*CC + l*8);
    bf16x8 fB = *(const bf16x8*)(featb + (size_t)sB*CC + l*8);
    #pragma unroll
    for (int i=0;i<8;i++){
      r[i] = fmaf(bf2f((unsigned short)fA[i]), aA, r[i]);
      r[i] = fmaf(bf2f((unsigned short)fB[i]), aB, r[i]);
    }
  }
  if (j < e1){
    int sA = csr[j];
    float aA = alpha[j*4 + h];
    ssum += aA;
    bf16x8 fA = *(const bf16x8*)(featb + (size_t)sA*CC + l*8);
    #pragma unroll
    for (int i=0;i<8;i++) r[i] = fmaf(bf2f((unsigned short)fA[i]), aA, r[i]);
  }
  float inv = (e1 > e0) ? 1.f/ssum : 0.f;
  bf16x8 rv = *(const bf16x8*)(resb + (size_t)n*CC + l*8);
  bf16x8 hb8;
  #pragma unroll
  for (int i=0;i<8;i++){
    float v = bf2f((unsigned short)rv[i]) + r[i]*inv;
    v = v > 0.f ? v : __expf(v)-1.f;
    hb8[i] = (short)f2bf(v);
  }
  *(bf16x8*)(hb + (size_t)n*CC + l*8) = hb8;
}

// ---- layer2 aggregation + readout + output: ONE BLOCK PER GRAPH,
//      16 lanes/node (8 ch/lane), alpha precomputed ----
__global__ __launch_bounds__(256) void k_aggr2(
    const int* __restrict__ gptr, const int* __restrict__ rowptr,
    const int* __restrict__ csr, const float* __restrict__ alpha,
    const unsigned short* __restrict__ featb,
    const unsigned short* __restrict__ hb,
    const float* __restrict__ b2, const float* __restrict__ aww,
    const float* __restrict__ awb,
    const float* __restrict__ outw, const float* __restrict__ outb,
    float* __restrict__ out)
{
  __shared__ float lsum[16][32];
  __shared__ float lmax[16][32];
  __shared__ float gv[64];
  __shared__ float rr1[2], rr2[2];
  int g = blockIdx.x;
  int n0 = gptr[g], n1 = gptr[g+1];
  int t = threadIdx.x;
  int grp = t>>4, l = t&15, h = l>>2;
  float gs[8] = {0.f,0.f,0.f,0.f,0.f,0.f,0.f,0.f};
  float gm[8] = {-3.4e38f,-3.4e38f,-3.4e38f,-3.4e38f,-3.4e38f,-3.4e38f,-3.4e38f,-3.4e38f};
  float bvv[8], awv[8];
  #pragma unroll
  for (int i=0;i<8;i++){
    bvv[i] = b2[l*8+i];
    awv[i] = aww[(l&3)*8+i];
  }
  float awbv = awb[0];
  for (int n = n0+grp; n < n1; n += 16){
    int e0 = rowptr[n], e1 = rowptr[n+1];
    float ssum = 0.f;
    float r[8] = {0.f,0.f,0.f,0.f,0.f,0.f,0.f,0.f};
    int j = e0;
    for (; j+2 <= e1; j += 2){
      int sA = csr[j], sB = csr[j+1];
      float aA = alpha[j*4 + h], aB = alpha[(j+1)*4 + h];
      ssum += aA + aB;
      bf16x8 fA = *(const bf16x8*)(featb + (size_t)sA*CC + l*8);
      bf16x8 fB = *(const bf16x8*)(featb + (size_t)sB*CC + l*8);
      #pragma unroll
      for (int i=0;i<8;i++){
        r[i] = fmaf(bf2f((unsigned short)fA[i]), aA, r[i]);
        r[i] = fmaf(bf2f((unsigned short)fB[i]), aB, r[i]);
      }
    }
    if (j < e1){
      int sA = csr[j];
      float aA = alpha[j*4 + h];
      ssum += aA;
      bf16x8 fA = *(const bf16x8*)(featb + (size_t)sA*CC + l*8);
      #pragma unroll
      for (int i=0;i<8;i++) r[i] = fmaf(bf2f((unsigned short)fA[i]), aA, r[i]);
    }
    float inv = (e1 > e0) ? 1.f/ssum : 0.f;
    bf16x8 hv = *(const bf16x8*)(hb + (size_t)n*CC + l*8);
    float p = 0.f;
    float hm[8];
    #pragma unroll
    for (int i=0;i<8;i++){
      float v = bf2f((unsigned short)hv[i]) + bvv[i] + r[i]*inv;
      v += __shfl_xor(v, 4, 16);
      v += __shfl_xor(v, 8, 16);
      hm[i] = 0.25f*v;
      p = fmaf(hm[i], awv[i], p);
    }
    p += __shfl_xor(p, 1, 16);
    p += __shfl_xor(p, 2, 16);
    float wgt = 1.f/(1.f + __expf(-(p + awbv)));
    #pragma unroll
    for (int i=0;i<8;i++){
      gs[i] = fmaf(wgt, hm[i], gs[i]);
      gm[i] = fmaxf(gm[i], hm[i]);
    }
  }
  if (l < 4){
    #pragma unroll
    for (int i=0;i<8;i++){
      lsum[grp][l*8+i] = gs[i];
      lmax[grp][l*8+i] = gm[i];
    }
  }
  __syncthreads();
  if (t < 32){
    float s=0.f, m=-3.4e38f;
    #pragma unroll
    for (int q=0;q<16;q++){ s += lsum[q][t]; m = fmaxf(m, lmax[q][t]); }
    gv[t]    = s;
    gv[32+t] = (m < -3.0e38f) ? 0.f : m;
  }
  __syncthreads();
  float y = 0.f;
  if (t < 128){
    y = outb[t];
    #pragma unroll
    for (int jj=0;jj<64;jj++) y = fmaf(gv[jj], outw[t*64+jj], y);
    float s1 = y, s2 = y*y;
    #pragma unroll
    for (int o=32;o;o>>=1){ s1 += __shfl_xor(s1,o); s2 += __shfl_xor(s2,o); }
    if ((t&63)==0){ rr1[t>>6]=s1; rr2[t>>6]=s2; }
  }
  __syncthreads();
  if (t < 128){
    float S1 = rr1[0]+rr1[1], S2 = rr2[0]+rr2[1];
    float mu = S1*(1.f/128.f);
    float var = S2*(1.f/128.f) - mu*mu;
    out[g*CC + t] = (y - mu) * rsqrtf(var + 1e-5f);
  }
}

extern "C" void kernel_launch(void* const* d_in, const int* in_sizes, int n_in,
                              void* d_out, int out_size, void* d_ws, size_t ws_size,
                              hipStream_t stream){
  const float* x     = (const float*)d_in[0];
  const int*   src   = (const int*)d_in[1];
  const int*   dst   = (const int*)d_in[2];
  const int*   gid   = (const int*)d_in[3];
  const float* fc1w  = (const float*)d_in[4];
  const float* al1   = (const float*)d_in[5];
  const float* ar1   = (const float*)d_in[6];
  const float* res1w = (const float*)d_in[7];
  const float* b1    = (const float*)d_in[8];
  const float* fc2w  = (const float*)d_in[9];
  const float* al2   = (const float*)d_in[10];
  const float* ar2   = (const float*)d_in[11];
  const float* b2    = (const float*)d_in[12];
  const float* aww   = (const float*)d_in[13];
  const float* awb   = (const float*)d_in[14];
  const float* outw  = (const float*)d_in[15];
  const float* outb  = (const float*)d_in[16];
  float* out = (float*)d_out;

  char* w = (char*)d_ws;
  unsigned short* featb = (unsigned short*)w;  w += (size_t)NN*CC*2;   // 25.6MB
  unsigned short* hb    = (unsigned short*)w;  w += (size_t)NN*CC*2;   // 25.6MB
  unsigned short* resb  = (unsigned short*)w;  w += (size_t)NN*CC*2;   // 25.6MB
  float*          el    = (float*)w;           w += (size_t)NN*HH*4;
  float*          er    = (float*)w;           w += (size_t)NN*HH*4;
  int*            deg   = (int*)w;             w += (size_t)NN*4;
  int*            rowptr= (int*)w;             w += (size_t)(NN+1)*4;
  int*            cursor= (int*)w;             w += (size_t)NN*4;
  int*            bsum  = (int*)w;             w += 128*4;
  int*            csr   = (int*)w;             w += (size_t)EE*4;
  int*            csrd  = (int*)w;             w += (size_t)EE*4;
  float*          alpha = (float*)w;           w += (size_t)EE*4*4;    // 6.4MB
  int*            gptr  = (int*)w;             w += (size_t)(GG+1)*4;
  unsigned short* wb2   = (unsigned short*)w;  w += (size_t)CC*CC*2;
  unsigned short* xb    = (unsigned short*)w;  w += (size_t)NN*32*2;   // 6.4MB
  unsigned short* wb1   = (unsigned short*)w;  w += (size_t)CC*32*2;
  unsigned short* wrb   = (unsigned short*)w;  w += (size_t)CC*32*2;

  const int EB = (EE + 255)/256;

  // fused prep (deg zero, gptr, bf16 converts) + CSR build
  k_prep<<<(NN*32+255)/256,256,0,stream>>>(x, fc1w, res1w, fc2w, gid,
                                           xb, wb1, wrb, wb2, deg, gptr);
  k_count<<<EB,256,0,stream>>>(dst, deg);
  k_scan_local<<<NB,256,0,stream>>>(deg, rowptr, bsum);
  k_scan_bsums<<<1,64,0,stream>>>(bsum, rowptr);
  k_scan_add<<<NB,256,0,stream>>>(rowptr, bsum, cursor);
  k_scatter<<<EB,256,0,stream>>>(src, dst, cursor, csr, csrd);

  // layer 1 (MFMA) + edge alphas + aggregation
  k_feat1m<<<1024,256,0,stream>>>(xb, wb1, wrb, b1, al1, ar1, featb, resb, el, er);
  k_alpha<<<EB,256,0,stream>>>(csr, csrd, el, er, (float4*)alpha);
  k_aggr1<<<(NN+15)/16,256,0,stream>>>(rowptr, csr, alpha, featb, resb, hb);
  // layer 2
  k_feat2<<<(NN/16*2+3)/4,256,0,stream>>>(hb, wb2, al2, ar2, featb, el, er);
  k_alpha<<<EB,256,0,stream>>>(csr, csrd, el, er, (float4*)alpha);
  // fused aggregation + readout + gnn_last + LayerNorm (block per graph)
  k_aggr2<<<GG,256,0,stream>>>(gptr, rowptr, csr, alpha, featb, hb,
                               b2, aww, awb, outw, outb, out);
}

// Round 15
// 210.224 us; speedup vs baseline: 1.0137x; 1.0137x over previous
//
#include <hip/hip_runtime.h>
#include <math.h>

#define NN 100000
#define EE 400000
#define GG 4096
#define INF_ 27
#define CC 128   // H*D
#define HH 4
#define DD 32
#define NB 98    // ceil(NN/1024) scan blocks

typedef short bf16x8 __attribute__((ext_vector_type(8)));
typedef float f32x4 __attribute__((ext_vector_type(4)));

// ---- bf16 helpers (RNE) ----
static __device__ __forceinline__ unsigned short f2bf(float f){
  unsigned u = __float_as_uint(f);
  u += 0x7fffu + ((u>>16)&1u);
  return (unsigned short)(u>>16);
}
static __device__ __forceinline__ float bf2f(unsigned short s){
  return __uint_as_float(((unsigned)s)<<16);
}

// ---- fused prep: zero deg, graph boundaries, x->bf16(pad32), w1/res1/w2->bf16 ----
__global__ __launch_bounds__(256) void k_prep(
    const float* __restrict__ x, const float* __restrict__ fcw,
    const float* __restrict__ resw, const float* __restrict__ w2,
    const int* __restrict__ gid,
    unsigned short* __restrict__ xb, unsigned short* __restrict__ wb1,
    unsigned short* __restrict__ wrb, unsigned short* __restrict__ wb2,
    int* __restrict__ deg, int* __restrict__ gptr)
{
  int i = blockIdx.x*256 + threadIdx.x;
  if (i < NN*32){
    int n = i>>5, k = i&31;
    xb[i] = (k<INF_) ? f2bf(x[n*INF_+k]) : (unsigned short)0;
  }
  if (i < NN){
    deg[i] = 0;
    int g = gid[i];
    int gp = (i==0) ? -1 : gid[i-1];
    for (int q=gp+1; q<=g; q++) gptr[q] = i;
    if (i==NN-1){
      for (int q=g+1; q<=GG; q++) gptr[q] = NN;
    }
  }
  if (i < CC*CC) wb2[i] = f2bf(w2[i]);
  if (i < CC*32){
    int c = i>>5, k = i&31;
    wb1[i] = (k<INF_) ? f2bf(fcw[c*INF_+k]) : (unsigned short)0;
    wrb[i] = (k<INF_) ? f2bf(resw[c*INF_+k]) : (unsigned short)0;
  }
}

__global__ void k_count(const int* __restrict__ dst, int* __restrict__ deg){
  int i = blockIdx.x*blockDim.x + threadIdx.x;
  if (i < EE) atomicAdd(&deg[dst[i]], 1);
}

__global__ __launch_bounds__(256) void k_scan_local(const int* __restrict__ deg,
                                                    int* __restrict__ rowptr,
                                                    int* __restrict__ bsum){
  __shared__ int sh[256];
  int t = threadIdx.x;
  int idx = blockIdx.x*1024 + t*4;
  int v0 = (idx+0<NN)?deg[idx+0]:0;
  int v1 = (idx+1<NN)?deg[idx+1]:0;
  int v2 = (idx+2<NN)?deg[idx+2]:0;
  int v3 = (idx+3<NN)?deg[idx+3]:0;
  sh[t] = v0+v1+v2+v3;
  __syncthreads();
  for (int o=1;o<256;o<<=1){
    int x = (t>=o)? sh[t-o] : 0;
    __syncthreads();
    sh[t] += x;
    __syncthreads();
  }
  int run = (t==0)? 0 : sh[t-1];
  if (t==255) bsum[blockIdx.x] = sh[255];
  if (idx+0<NN){ rowptr[idx+0]=run; run+=v0; }
  if (idx+1<NN){ rowptr[idx+1]=run; run+=v1; }
  if (idx+2<NN){ rowptr[idx+2]=run; run+=v2; }
  if (idx+3<NN){ rowptr[idx+3]=run; }
}

__global__ void k_scan_bsums(int* __restrict__ bsum, int* __restrict__ rowptr){
  if (threadIdx.x==0 && blockIdx.x==0){
    int run = 0;
    for (int b=0;b<NB;b++){ int v=bsum[b]; bsum[b]=run; run+=v; }
    rowptr[NN] = run;
  }
}

__global__ __launch_bounds__(256) void k_scan_add(int* __restrict__ rowptr,
                                                  const int* __restrict__ bsum,
                                                  int* __restrict__ cursor){
  int idx = blockIdx.x*1024 + threadIdx.x*4;
  int off = bsum[blockIdx.x];
  #pragma unroll
  for (int i=0;i<4;i++){
    if (idx+i<NN){ int r = rowptr[idx+i]+off; rowptr[idx+i]=r; cursor[idx+i]=r; }
  }
}

__global__ void k_scatter(const int* __restrict__ src, const int* __restrict__ dst,
                          int* __restrict__ cursor, int* __restrict__ csr_src){
  int i = blockIdx.x*blockDim.x + threadIdx.x;
  if (i < EE){
    int pos = atomicAdd(&cursor[dst[i]], 1);
    csr_src[pos] = src[i];
  }
}

// ---- layer1 via MFMA: featb = bf16(x@fc1^T), resb = bf16(x@res1^T + b1), el/er ----
__global__ __launch_bounds__(256) void k_feat1m(
    const unsigned short* __restrict__ xb, const unsigned short* __restrict__ wb1,
    const unsigned short* __restrict__ wrb, const float* __restrict__ bias,
    const float* __restrict__ al, const float* __restrict__ ar,
    unsigned short* __restrict__ featb, unsigned short* __restrict__ resb,
    float* __restrict__ el, float* __restrict__ er)
{
  int wid = (blockIdx.x*256 + threadIdx.x) >> 6;
  int lane = threadIdx.x & 63;
  int l15 = lane & 15, khi = lane >> 4;
  int nw = gridDim.x*4;
  bf16x8 wf[8], wr[8];
  float bv8[8];
  #pragma unroll
  for (int ct=0; ct<8; ct++){
    wf[ct] = *(const bf16x8*)(wb1 + (ct*16+l15)*32 + khi*8);
    wr[ct] = *(const bf16x8*)(wrb + (ct*16+l15)*32 + khi*8);
    bv8[ct] = bias[ct*16+l15];
  }
  float a0v[4], a1v[4], b0v[4], b1v[4];
  #pragma unroll
  for (int hh=0; hh<4; hh++){
    int c0 = hh*32 + l15;
    a0v[hh] = al[c0]; a1v[hh] = al[c0+16];
    b0v[hh] = ar[c0]; b1v[hh] = ar[c0+16];
  }
  for (int tile = wid; tile < NN/16; tile += nw){
    int n0 = tile*16;
    bf16x8 af = *(const bf16x8*)(xb + (size_t)(n0+l15)*32 + khi*8);
    f32x4 accf[8], accr[8];
    #pragma unroll
    for (int ct=0; ct<8; ct++){
      accf[ct] = __builtin_amdgcn_mfma_f32_16x16x32_bf16(af, wf[ct], (f32x4){0.f,0.f,0.f,0.f}, 0,0,0);
      accr[ct] = __builtin_amdgcn_mfma_f32_16x16x32_bf16(af, wr[ct], (f32x4){0.f,0.f,0.f,0.f}, 0,0,0);
    }
    #pragma unroll
    for (int ct=0; ct<8; ct++){
      int c = ct*16+l15;
      #pragma unroll
      for (int r=0;r<4;r++){
        int n = n0 + khi*4 + r;
        featb[(size_t)n*CC + c] = f2bf(accf[ct][r]);
        resb [(size_t)n*CC + c] = f2bf(accr[ct][r] + bv8[ct]);
      }
    }
    #pragma unroll
    for (int hh=0; hh<4; hh++){
      #pragma unroll
      for (int r=0;r<4;r++){
        float pe = accf[2*hh][r]*a0v[hh] + accf[2*hh+1][r]*a1v[hh];
        float pr = accf[2*hh][r]*b0v[hh] + accf[2*hh+1][r]*b1v[hh];
        #pragma unroll
        for (int o=8;o;o>>=1){ pe += __shfl_xor(pe,o,16); pr += __shfl_xor(pr,o,16); }
        if (l15==0){
          int n = n0 + khi*4 + r;
          el[n*HH + hh] = pe;
          er[n*HH + hh] = pr;
        }
      }
    }
  }
}

// ---- layer2 GEMM via MFMA: featb = bf16(hb @ fc2^T), el/er dots ----
__global__ __launch_bounds__(256) void k_feat2(
    const unsigned short* __restrict__ hb, const unsigned short* __restrict__ wb2,
    const float* __restrict__ al, const float* __restrict__ ar,
    unsigned short* __restrict__ featb, float* __restrict__ el, float* __restrict__ er)
{
  int wid = (blockIdx.x*256 + threadIdx.x) >> 6;
  int lane = threadIdx.x & 63;
  int tile = wid >> 1;
  int ch = wid & 1;
  if (tile >= NN/16) return;
  int l15 = lane & 15, khi = lane >> 4;
  int n0 = tile*16;
  bf16x8 wf[4][4];
  #pragma unroll
  for (int ct=0; ct<4; ct++)
    #pragma unroll
    for (int ks=0; ks<4; ks++)
      wf[ct][ks] = *(const bf16x8*)(wb2 + (size_t)(ch*64+ct*16+l15)*CC + ks*32 + khi*8);
  bf16x8 af[4];
  #pragma unroll
  for (int ks=0; ks<4; ks++)
    af[ks] = *(const bf16x8*)(hb + (size_t)(n0+l15)*CC + ks*32 + khi*8);
  f32x4 accf[4] = {{0.f,0.f,0.f,0.f},{0.f,0.f,0.f,0.f},{0.f,0.f,0.f,0.f},{0.f,0.f,0.f,0.f}};
  #pragma unroll
  for (int ks=0; ks<4; ks++)
    #pragma unroll
    for (int ct=0; ct<4; ct++)
      accf[ct] = __builtin_amdgcn_mfma_f32_16x16x32_bf16(af[ks], wf[ct][ks], accf[ct], 0,0,0);
  #pragma unroll
  for (int ct=0; ct<4; ct++)
    #pragma unroll
    for (int r=0;r<4;r++)
      featb[(size_t)(n0+khi*4+r)*CC + ch*64+ct*16+l15] = f2bf(accf[ct][r]);
  #pragma unroll
  for (int hh=0; hh<2; hh++){
    int c0 = ch*64 + hh*32 + l15;
    float a0 = al[c0], a1 = al[c0+16], b0 = ar[c0], b1 = ar[c0+16];
    #pragma unroll
    for (int r=0;r<4;r++){
      float pe = accf[2*hh][r]*a0 + accf[2*hh+1][r]*a1;
      float pr = accf[2*hh][r]*b0 + accf[2*hh+1][r]*b1;
      #pragma unroll
      for (int o=8;o;o>>=1){ pe += __shfl_xor(pe,o,16); pr += __shfl_xor(pr,o,16); }
      if (l15==0){
        int n = n0 + khi*4 + r;
        el[n*HH + ch*2+hh] = pe;
        er[n*HH + ch*2+hh] = pr;
      }
    }
  }
}

// ---- layer1 aggregation: 8 lanes/node, 16 ch/lane (2x bf16x8 loads/edge).
//      single-pass softmax; epilogue elu(res + rst) -> hb(bf16). ----
__global__ __launch_bounds__(256) void k_aggr1(
    const int* __restrict__ rowptr, const int* __restrict__ csr,
    const float* __restrict__ el, const float* __restrict__ er,
    const unsigned short* __restrict__ featb,
    const unsigned short* __restrict__ resb,
    unsigned short* __restrict__ hb)
{
  int t = threadIdx.x;
  int n = blockIdx.x*32 + (t>>3);
  if (n >= NN) return;
  int l = t & 7;
  int h = l >> 1;
  int e0 = rowptr[n], e1 = rowptr[n+1];
  float ern = er[n*HH + h];
  float ssum = 0.f;
  float r[16];
  #pragma unroll
  for (int i=0;i<16;i++) r[i]=0.f;
  int j = e0;
  for (; j+2 <= e1; j += 2){
    int sA = csr[j], sB = csr[j+1];
    float vA = el[sA*HH+h] + ern; vA = vA>0.f?vA:0.2f*vA;
    float vB = el[sB*HH+h] + ern; vB = vB>0.f?vB:0.2f*vB;
    float aA = __expf(vA), aB = __expf(vB);
    ssum += aA + aB;
    const unsigned short* pA = featb + (size_t)sA*CC + l*16;
    const unsigned short* pB = featb + (size_t)sB*CC + l*16;
    bf16x8 fA0 = *(const bf16x8*)(pA);
    bf16x8 fA1 = *(const bf16x8*)(pA+8);
    bf16x8 fB0 = *(const bf16x8*)(pB);
    bf16x8 fB1 = *(const bf16x8*)(pB+8);
    #pragma unroll
    for (int i=0;i<8;i++){
      r[i]   = fmaf(bf2f((unsigned short)fA0[i]), aA, r[i]);
      r[8+i] = fmaf(bf2f((unsigned short)fA1[i]), aA, r[8+i]);
      r[i]   = fmaf(bf2f((unsigned short)fB0[i]), aB, r[i]);
      r[8+i] = fmaf(bf2f((unsigned short)fB1[i]), aB, r[8+i]);
    }
  }
  if (j < e1){
    int sA = csr[j];
    float vA = el[sA*HH+h] + ern; vA = vA>0.f?vA:0.2f*vA;
    float aA = __expf(vA);
    ssum += aA;
    const unsigned short* pA = featb + (size_t)sA*CC + l*16;
    bf16x8 fA0 = *(const bf16x8*)(pA);
    bf16x8 fA1 = *(const bf16x8*)(pA+8);
    #pragma unroll
    for (int i=0;i<8;i++){
      r[i]   = fmaf(bf2f((unsigned short)fA0[i]), aA, r[i]);
      r[8+i] = fmaf(bf2f((unsigned short)fA1[i]), aA, r[8+i]);
    }
  }
  float inv = (e1 > e0) ? 1.f/ssum : 0.f;
  const unsigned short* pr = resb + (size_t)n*CC + l*16;
  bf16x8 rv0 = *(const bf16x8*)(pr);
  bf16x8 rv1 = *(const bf16x8*)(pr+8);
  bf16x8 o0, o1;
  #pragma unroll
  for (int i=0;i<8;i++){
    float v0 = bf2f((unsigned short)rv0[i]) + r[i]*inv;
    float v1 = bf2f((unsigned short)rv1[i]) + r[8+i]*inv;
    v0 = v0 > 0.f ? v0 : __expf(v0)-1.f;
    v1 = v1 > 0.f ? v1 : __expf(v1)-1.f;
    o0[i] = (short)f2bf(v0);
    o1[i] = (short)f2bf(v1);
  }
  unsigned short* ph = hb + (size_t)n*CC + l*16;
  *(bf16x8*)(ph)   = o0;
  *(bf16x8*)(ph+8) = o1;
}

// ---- layer2 aggregation + readout + output: ONE BLOCK PER GRAPH,
//      8 lanes/node (16 ch/lane), graph sum/max in regs + LDS combine ----
__global__ __launch_bounds__(256) void k_aggr2(
    const int* __restrict__ gptr, const int* __restrict__ rowptr,
    const int* __restrict__ csr,
    const float* __restrict__ el, const float* __restrict__ er,
    const unsigned short* __restrict__ featb,
    const unsigned short* __restrict__ hb,
    const float* __restrict__ b2, const float* __restrict__ aww,
    const float* __restrict__ awb,
    const float* __restrict__ outw, const float* __restrict__ outb,
    float* __restrict__ out)
{
  __shared__ float lsum[32][32];
  __shared__ float lmax[32][32];
  __shared__ float gv[64];
  __shared__ float rr1[2], rr2[2];
  int g = blockIdx.x;
  int n0 = gptr[g], n1 = gptr[g+1];
  int t = threadIdx.x;
  int grp = t>>3, l = t&7, h = l>>1;
  float gs[16], gm[16], bvv[16], awv[16];
  #pragma unroll
  for (int i=0;i<16;i++){
    gs[i]=0.f; gm[i]=-3.4e38f;
    bvv[i] = b2[l*16+i];
    awv[i] = aww[(l&1)*16+i];
  }
  float awbv = awb[0];
  for (int n = n0+grp; n < n1; n += 32){
    int e0 = rowptr[n], e1 = rowptr[n+1];
    float ern = er[n*HH + h];
    float ssum = 0.f;
    float r[16];
    #pragma unroll
    for (int i=0;i<16;i++) r[i]=0.f;
    int j = e0;
    for (; j+2 <= e1; j += 2){
      int sA = csr[j], sB = csr[j+1];
      float vA = el[sA*HH+h] + ern; vA = vA>0.f?vA:0.2f*vA;
      float vB = el[sB*HH+h] + ern; vB = vB>0.f?vB:0.2f*vB;
      float aA = __expf(vA), aB = __expf(vB);
      ssum += aA + aB;
      const unsigned short* pA = featb + (size_t)sA*CC + l*16;
      const unsigned short* pB = featb + (size_t)sB*CC + l*16;
      bf16x8 fA0 = *(const bf16x8*)(pA);
      bf16x8 fA1 = *(const bf16x8*)(pA+8);
      bf16x8 fB0 = *(const bf16x8*)(pB);
      bf16x8 fB1 = *(const bf16x8*)(pB+8);
      #pragma unroll
      for (int i=0;i<8;i++){
        r[i]   = fmaf(bf2f((unsigned short)fA0[i]), aA, r[i]);
        r[8+i] = fmaf(bf2f((unsigned short)fA1[i]), aA, r[8+i]);
        r[i]   = fmaf(bf2f((unsigned short)fB0[i]), aB, r[i]);
        r[8+i] = fmaf(bf2f((unsigned short)fB1[i]), aB, r[8+i]);
      }
    }
    if (j < e1){
      int sA = csr[j];
      float vA = el[sA*HH+h] + ern; vA = vA>0.f?vA:0.2f*vA;
      float aA = __expf(vA);
      ssum += aA;
      const unsigned short* pA = featb + (size_t)sA*CC + l*16;
      bf16x8 fA0 = *(const bf16x8*)(pA);
      bf16x8 fA1 = *(const bf16x8*)(pA+8);
      #pragma unroll
      for (int i=0;i<8;i++){
        r[i]   = fmaf(bf2f((unsigned short)fA0[i]), aA, r[i]);
        r[8+i] = fmaf(bf2f((unsigned short)fA1[i]), aA, r[8+i]);
      }
    }
    float inv = (e1 > e0) ? 1.f/ssum : 0.f;
    const unsigned short* ph = hb + (size_t)n*CC + l*16;
    bf16x8 hv0 = *(const bf16x8*)(ph);
    bf16x8 hv1 = *(const bf16x8*)(ph+8);
    float p = 0.f;
    float hm[16];
    #pragma unroll
    for (int i=0;i<16;i++){
      float base = (i<8) ? bf2f((unsigned short)hv0[i]) : bf2f((unsigned short)hv1[i-8]);
      float v = base + bvv[i] + r[i]*inv;
      // head-sum: heads live in lanes differing in bits 1-2 of l
      v += __shfl_xor(v, 2, 8);
      v += __shfl_xor(v, 4, 8);
      hm[i] = 0.25f*v;
      p = fmaf(hm[i], awv[i], p);
    }
    // gate dot: other d-half lives in lane^1
    p += __shfl_xor(p, 1, 8);
    float wgt = 1.f/(1.f + __expf(-(p + awbv)));
    #pragma unroll
    for (int i=0;i<16;i++){
      gs[i] = fmaf(wgt, hm[i], gs[i]);
      gm[i] = fmaxf(gm[i], hm[i]);
    }
  }
  if (l < 2){
    #pragma unroll
    for (int i=0;i<16;i++){
      lsum[grp][l*16+i] = gs[i];
      lmax[grp][l*16+i] = gm[i];
    }
  }
  __syncthreads();
  if (t < 32){
    float s=0.f, m=-3.4e38f;
    #pragma unroll
    for (int q=0;q<32;q++){ s += lsum[q][t]; m = fmaxf(m, lmax[q][t]); }
    gv[t]    = s;
    gv[32+t] = (m < -3.0e38f) ? 0.f : m;
  }
  __syncthreads();
  float y = 0.f;
  if (t < 128){
    y = outb[t];
    #pragma unroll
    for (int jj=0;jj<64;jj++) y = fmaf(gv[jj], outw[t*64+jj], y);
    float s1 = y, s2 = y*y;
    #pragma unroll
    for (int o=32;o;o>>=1){ s1 += __shfl_xor(s1,o); s2 += __shfl_xor(s2,o); }
    if ((t&63)==0){ rr1[t>>6]=s1; rr2[t>>6]=s2; }
  }
  __syncthreads();
  if (t < 128){
    float S1 = rr1[0]+rr1[1], S2 = rr2[0]+rr2[1];
    float mu = S1*(1.f/128.f);
    float var = S2*(1.f/128.f) - mu*mu;
    out[g*CC + t] = (y - mu) * rsqrtf(var + 1e-5f);
  }
}

extern "C" void kernel_launch(void* const* d_in, const int* in_sizes, int n_in,
                              void* d_out, int out_size, void* d_ws, size_t ws_size,
                              hipStream_t stream){
  const float* x     = (const float*)d_in[0];
  const int*   src   = (const int*)d_in[1];
  const int*   dst   = (const int*)d_in[2];
  const int*   gid   = (const int*)d_in[3];
  const float* fc1w  = (const float*)d_in[4];
  const float* al1   = (const float*)d_in[5];
  const float* ar1   = (const float*)d_in[6];
  const float* res1w = (const float*)d_in[7];
  const float* b1    = (const float*)d_in[8];
  const float* fc2w  = (const float*)d_in[9];
  const float* al2   = (const float*)d_in[10];
  const float* ar2   = (const float*)d_in[11];
  const float* b2    = (const float*)d_in[12];
  const float* aww   = (const float*)d_in[13];
  const float* awb   = (const float*)d_in[14];
  const float* outw  = (const float*)d_in[15];
  const float* outb  = (const float*)d_in[16];
  float* out = (float*)d_out;

  char* w = (char*)d_ws;
  unsigned short* featb = (unsigned short*)w;  w += (size_t)NN*CC*2;   // 25.6MB
  unsigned short* hb    = (unsigned short*)w;  w += (size_t)NN*CC*2;   // 25.6MB
  unsigned short* resb  = (unsigned short*)w;  w += (size_t)NN*CC*2;   // 25.6MB
  float*          el    = (float*)w;           w += (size_t)NN*HH*4;
  float*          er    = (float*)w;           w += (size_t)NN*HH*4;
  int*            deg   = (int*)w;             w += (size_t)NN*4;
  int*            rowptr= (int*)w;             w += (size_t)(NN+1)*4;
  int*            cursor= (int*)w;             w += (size_t)NN*4;
  int*            bsum  = (int*)w;             w += 128*4;
  int*            csr   = (int*)w;             w += (size_t)EE*4;
  int*            gptr  = (int*)w;             w += (size_t)(GG+1)*4;
  unsigned short* wb2   = (unsigned short*)w;  w += (size_t)CC*CC*2;
  unsigned short* xb    = (unsigned short*)w;  w += (size_t)NN*32*2;   // 6.4MB
  unsigned short* wb1   = (unsigned short*)w;  w += (size_t)CC*32*2;
  unsigned short* wrb   = (unsigned short*)w;  w += (size_t)CC*32*2;

  const int EB = (EE + 255)/256;

  // fused prep (deg zero, gptr, bf16 converts) + CSR build
  k_prep<<<(NN*32+255)/256,256,0,stream>>>(x, fc1w, res1w, fc2w, gid,
                                           xb, wb1, wrb, wb2, deg, gptr);
  k_count<<<EB,256,0,stream>>>(dst, deg);
  k_scan_local<<<NB,256,0,stream>>>(deg, rowptr, bsum);
  k_scan_bsums<<<1,64,0,stream>>>(bsum, rowptr);
  k_scan_add<<<NB,256,0,stream>>>(rowptr, bsum, cursor);
  k_scatter<<<EB,256,0,stream>>>(src, dst, cursor, csr);

  // layer 1 (MFMA)
  k_feat1m<<<1024,256,0,stream>>>(xb, wb1, wrb, b1, al1, ar1, featb, resb, el, er);
  k_aggr1<<<(NN+31)/32,256,0,stream>>>(rowptr, csr, el, er, featb, resb, hb);
  // layer 2
  k_feat2<<<(NN/16*2+3)/4,256,0,stream>>>(hb, wb2, al2, ar2, featb, el, er);
  // fused aggregation + readout + gnn_last + LayerNorm (block per graph)
  k_aggr2<<<GG,256,0,stream>>>(gptr, rowptr, csr, el, er, featb, hb,
                               b2, aww, awb, outw, outb, out);
}

// Round 16
// 202.995 us; speedup vs baseline: 1.0498x; 1.0356x over previous
//
#include <hip/hip_runtime.h>
#include <math.h>

#define NN 100000
#define EE 400000
#define GG 4096
#define INF_ 27
#define CC 128   // H*D
#define HH 4
#define DD 32
#define NB 98    // ceil(NN/1024) scan blocks

typedef short bf16x8 __attribute__((ext_vector_type(8)));
typedef float f32x4 __attribute__((ext_vector_type(4)));

// ---- bf16 helpers (RNE) ----
static __device__ __forceinline__ unsigned short f2bf(float f){
  unsigned u = __float_as_uint(f);
  u += 0x7fffu + ((u>>16)&1u);
  return (unsigned short)(u>>16);
}
static __device__ __forceinline__ float bf2f(unsigned short s){
  return __uint_as_float(((unsigned)s)<<16);
}

// ---- fused prep: zero deg, graph boundaries, x->bf16(pad32), w1/res1/w2->bf16 ----
__global__ __launch_bounds__(256) void k_prep(
    const float* __restrict__ x, const float* __restrict__ fcw,
    const float* __restrict__ resw, const float* __restrict__ w2,
    const int* __restrict__ gid,
    unsigned short* __restrict__ xb, unsigned short* __restrict__ wb1,
    unsigned short* __restrict__ wrb, unsigned short* __restrict__ wb2,
    int* __restrict__ deg, int* __restrict__ gptr)
{
  int i = blockIdx.x*256 + threadIdx.x;
  if (i < NN*32){
    int n = i>>5, k = i&31;
    xb[i] = (k<INF_) ? f2bf(x[n*INF_+k]) : (unsigned short)0;
  }
  if (i < NN){
    deg[i] = 0;
    int g = gid[i];
    int gp = (i==0) ? -1 : gid[i-1];
    for (int q=gp+1; q<=g; q++) gptr[q] = i;
    if (i==NN-1){
      for (int q=g+1; q<=GG; q++) gptr[q] = NN;
    }
  }
  if (i < CC*CC) wb2[i] = f2bf(w2[i]);
  if (i < CC*32){
    int c = i>>5, k = i&31;
    wb1[i] = (k<INF_) ? f2bf(fcw[c*INF_+k]) : (unsigned short)0;
    wrb[i] = (k<INF_) ? f2bf(resw[c*INF_+k]) : (unsigned short)0;
  }
}

__global__ void k_count(const int* __restrict__ dst, int* __restrict__ deg){
  int i = blockIdx.x*blockDim.x + threadIdx.x;
  if (i < EE) atomicAdd(&deg[dst[i]], 1);
}

__global__ __launch_bounds__(256) void k_scan_local(const int* __restrict__ deg,
                                                    int* __restrict__ rowptr,
                                                    int* __restrict__ bsum){
  __shared__ int sh[256];
  int t = threadIdx.x;
  int idx = blockIdx.x*1024 + t*4;
  int v0 = (idx+0<NN)?deg[idx+0]:0;
  int v1 = (idx+1<NN)?deg[idx+1]:0;
  int v2 = (idx+2<NN)?deg[idx+2]:0;
  int v3 = (idx+3<NN)?deg[idx+3]:0;
  sh[t] = v0+v1+v2+v3;
  __syncthreads();
  for (int o=1;o<256;o<<=1){
    int x = (t>=o)? sh[t-o] : 0;
    __syncthreads();
    sh[t] += x;
    __syncthreads();
  }
  int run = (t==0)? 0 : sh[t-1];
  if (t==255) bsum[blockIdx.x] = sh[255];
  if (idx+0<NN){ rowptr[idx+0]=run; run+=v0; }
  if (idx+1<NN){ rowptr[idx+1]=run; run+=v1; }
  if (idx+2<NN){ rowptr[idx+2]=run; run+=v2; }
  if (idx+3<NN){ rowptr[idx+3]=run; }
}

__global__ void k_scan_bsums(int* __restrict__ bsum, int* __restrict__ rowptr){
  if (threadIdx.x==0 && blockIdx.x==0){
    int run = 0;
    for (int b=0;b<NB;b++){ int v=bsum[b]; bsum[b]=run; run+=v; }
    rowptr[NN] = run;
  }
}

__global__ __launch_bounds__(256) void k_scan_add(int* __restrict__ rowptr,
                                                  const int* __restrict__ bsum,
                                                  int* __restrict__ cursor){
  int idx = blockIdx.x*1024 + threadIdx.x*4;
  int off = bsum[blockIdx.x];
  #pragma unroll
  for (int i=0;i<4;i++){
    if (idx+i<NN){ int r = rowptr[idx+i]+off; rowptr[idx+i]=r; cursor[idx+i]=r; }
  }
}

__global__ void k_scatter(const int* __restrict__ src, const int* __restrict__ dst,
                          int* __restrict__ cursor, int* __restrict__ csr_src){
  int i = blockIdx.x*blockDim.x + threadIdx.x;
  if (i < EE){
    int pos = atomicAdd(&cursor[dst[i]], 1);
    csr_src[pos] = src[i];
  }
}

// ---- layer1 via MFMA: featb = bf16(x@fc1^T), resb = bf16(x@res1^T + b1), el/er ----
__global__ __launch_bounds__(256) void k_feat1m(
    const unsigned short* __restrict__ xb, const unsigned short* __restrict__ wb1,
    const unsigned short* __restrict__ wrb, const float* __restrict__ bias,
    const float* __restrict__ al, const float* __restrict__ ar,
    unsigned short* __restrict__ featb, unsigned short* __restrict__ resb,
    float* __restrict__ el, float* __restrict__ er)
{
  int wid = (blockIdx.x*256 + threadIdx.x) >> 6;
  int lane = threadIdx.x & 63;
  int l15 = lane & 15, khi = lane >> 4;
  int nw = gridDim.x*4;
  bf16x8 wf[8], wr[8];
  float bv8[8];
  #pragma unroll
  for (int ct=0; ct<8; ct++){
    wf[ct] = *(const bf16x8*)(wb1 + (ct*16+l15)*32 + khi*8);
    wr[ct] = *(const bf16x8*)(wrb + (ct*16+l15)*32 + khi*8);
    bv8[ct] = bias[ct*16+l15];
  }
  float a0v[4], a1v[4], b0v[4], b1v[4];
  #pragma unroll
  for (int hh=0; hh<4; hh++){
    int c0 = hh*32 + l15;
    a0v[hh] = al[c0]; a1v[hh] = al[c0+16];
    b0v[hh] = ar[c0]; b1v[hh] = ar[c0+16];
  }
  for (int tile = wid; tile < NN/16; tile += nw){
    int n0 = tile*16;
    bf16x8 af = *(const bf16x8*)(xb + (size_t)(n0+l15)*32 + khi*8);
    f32x4 accf[8], accr[8];
    #pragma unroll
    for (int ct=0; ct<8; ct++){
      accf[ct] = __builtin_amdgcn_mfma_f32_16x16x32_bf16(af, wf[ct], (f32x4){0.f,0.f,0.f,0.f}, 0,0,0);
      accr[ct] = __builtin_amdgcn_mfma_f32_16x16x32_bf16(af, wr[ct], (f32x4){0.f,0.f,0.f,0.f}, 0,0,0);
    }
    #pragma unroll
    for (int ct=0; ct<8; ct++){
      int c = ct*16+l15;
      #pragma unroll
      for (int r=0;r<4;r++){
        int n = n0 + khi*4 + r;
        featb[(size_t)n*CC + c] = f2bf(accf[ct][r]);
        resb [(size_t)n*CC + c] = f2bf(accr[ct][r] + bv8[ct]);
      }
    }
    #pragma unroll
    for (int hh=0; hh<4; hh++){
      #pragma unroll
      for (int r=0;r<4;r++){
        float pe = accf[2*hh][r]*a0v[hh] + accf[2*hh+1][r]*a1v[hh];
        float pr = accf[2*hh][r]*b0v[hh] + accf[2*hh+1][r]*b1v[hh];
        #pragma unroll
        for (int o=8;o;o>>=1){ pe += __shfl_xor(pe,o,16); pr += __shfl_xor(pr,o,16); }
        if (l15==0){
          int n = n0 + khi*4 + r;
          el[n*HH + hh] = pe;
          er[n*HH + hh] = pr;
        }
      }
    }
  }
}

// ---- layer2 GEMM via MFMA: featb = bf16(hb @ fc2^T), el/er dots ----
__global__ __launch_bounds__(256) void k_feat2(
    const unsigned short* __restrict__ hb, const unsigned short* __restrict__ wb2,
    const float* __restrict__ al, const float* __restrict__ ar,
    unsigned short* __restrict__ featb, float* __restrict__ el, float* __restrict__ er)
{
  int wid = (blockIdx.x*256 + threadIdx.x) >> 6;
  int lane = threadIdx.x & 63;
  int tile = wid >> 1;
  int ch = wid & 1;
  if (tile >= NN/16) return;
  int l15 = lane & 15, khi = lane >> 4;
  int n0 = tile*16;
  bf16x8 wf[4][4];
  #pragma unroll
  for (int ct=0; ct<4; ct++)
    #pragma unroll
    for (int ks=0; ks<4; ks++)
      wf[ct][ks] = *(const bf16x8*)(wb2 + (size_t)(ch*64+ct*16+l15)*CC + ks*32 + khi*8);
  bf16x8 af[4];
  #pragma unroll
  for (int ks=0; ks<4; ks++)
    af[ks] = *(const bf16x8*)(hb + (size_t)(n0+l15)*CC + ks*32 + khi*8);
  f32x4 accf[4] = {{0.f,0.f,0.f,0.f},{0.f,0.f,0.f,0.f},{0.f,0.f,0.f,0.f},{0.f,0.f,0.f,0.f}};
  #pragma unroll
  for (int ks=0; ks<4; ks++)
    #pragma unroll
    for (int ct=0; ct<4; ct++)
      accf[ct] = __builtin_amdgcn_mfma_f32_16x16x32_bf16(af[ks], wf[ct][ks], accf[ct], 0,0,0);
  #pragma unroll
  for (int ct=0; ct<4; ct++)
    #pragma unroll
    for (int r=0;r<4;r++)
      featb[(size_t)(n0+khi*4+r)*CC + ch*64+ct*16+l15] = f2bf(accf[ct][r]);
  #pragma unroll
  for (int hh=0; hh<2; hh++){
    int c0 = ch*64 + hh*32 + l15;
    float a0 = al[c0], a1 = al[c0+16], b0 = ar[c0], b1 = ar[c0+16];
    #pragma unroll
    for (int r=0;r<4;r++){
      float pe = accf[2*hh][r]*a0 + accf[2*hh+1][r]*a1;
      float pr = accf[2*hh][r]*b0 + accf[2*hh+1][r]*b1;
      #pragma unroll
      for (int o=8;o;o>>=1){ pe += __shfl_xor(pe,o,16); pr += __shfl_xor(pr,o,16); }
      if (l15==0){
        int n = n0 + khi*4 + r;
        el[n*HH + ch*2+hh] = pe;
        er[n*HH + ch*2+hh] = pr;
      }
    }
  }
}

// ---- edge-batch macro body: 16 lanes/node, 8 ch/lane; 4-wide load-all-then-
//      compute for deg>=4, then 2-wide, then 1 tail. ----
#define EDGE_LOOP(FETCH_ROW) \
  int j = e0; \
  for (; j+4 <= e1; j += 4){ \
    int s0j = csr[j], s1j = csr[j+1], s2j = csr[j+2], s3j = csr[j+3]; \
    float q0 = el[s0j*HH+h], q1 = el[s1j*HH+h], q2 = el[s2j*HH+h], q3 = el[s3j*HH+h]; \
    bf16x8 f0 = FETCH_ROW(s0j); bf16x8 f1 = FETCH_ROW(s1j); \
    bf16x8 f2 = FETCH_ROW(s2j); bf16x8 f3 = FETCH_ROW(s3j); \
    float v; float a0,a1,a2,a3; \
    v = q0+ern; v = v>0.f?v:0.2f*v; a0 = __expf(v); \
    v = q1+ern; v = v>0.f?v:0.2f*v; a1 = __expf(v); \
    v = q2+ern; v = v>0.f?v:0.2f*v; a2 = __expf(v); \
    v = q3+ern; v = v>0.f?v:0.2f*v; a3 = __expf(v); \
    ssum += (a0+a1)+(a2+a3); \
    _Pragma("unroll") \
    for (int i=0;i<8;i++){ \
      r[i] = fmaf(bf2f((unsigned short)f0[i]), a0, r[i]); \
      r[i] = fmaf(bf2f((unsigned short)f1[i]), a1, r[i]); \
      r[i] = fmaf(bf2f((unsigned short)f2[i]), a2, r[i]); \
      r[i] = fmaf(bf2f((unsigned short)f3[i]), a3, r[i]); \
    } \
  } \
  for (; j+2 <= e1; j += 2){ \
    int s0j = csr[j], s1j = csr[j+1]; \
    float q0 = el[s0j*HH+h], q1 = el[s1j*HH+h]; \
    bf16x8 f0 = FETCH_ROW(s0j); bf16x8 f1 = FETCH_ROW(s1j); \
    float v; float a0,a1; \
    v = q0+ern; v = v>0.f?v:0.2f*v; a0 = __expf(v); \
    v = q1+ern; v = v>0.f?v:0.2f*v; a1 = __expf(v); \
    ssum += a0+a1; \
    _Pragma("unroll") \
    for (int i=0;i<8;i++){ \
      r[i] = fmaf(bf2f((unsigned short)f0[i]), a0, r[i]); \
      r[i] = fmaf(bf2f((unsigned short)f1[i]), a1, r[i]); \
    } \
  } \
  if (j < e1){ \
    int s0j = csr[j]; \
    float q0 = el[s0j*HH+h]; \
    bf16x8 f0 = FETCH_ROW(s0j); \
    float v = q0+ern; v = v>0.f?v:0.2f*v; float a0 = __expf(v); \
    ssum += a0; \
    _Pragma("unroll") \
    for (int i=0;i<8;i++) r[i] = fmaf(bf2f((unsigned short)f0[i]), a0, r[i]); \
  }

// ---- layer1 aggregation: 16 lanes/node, 8 channels/lane ----
__global__ __launch_bounds__(256) void k_aggr1(
    const int* __restrict__ rowptr, const int* __restrict__ csr,
    const float* __restrict__ el, const float* __restrict__ er,
    const unsigned short* __restrict__ featb,
    const unsigned short* __restrict__ resb,
    unsigned short* __restrict__ hb)
{
  int t = threadIdx.x;
  int n = blockIdx.x*16 + (t>>4);
  if (n >= NN) return;
  int l = t & 15;
  int h = l >> 2;
  int e0 = rowptr[n], e1 = rowptr[n+1];
  float ern = er[n*HH + h];
  float ssum = 0.f;
  float r[8] = {0.f,0.f,0.f,0.f,0.f,0.f,0.f,0.f};
  #define ROW1(s) (*(const bf16x8*)(featb + (size_t)(s)*CC + l*8))
  EDGE_LOOP(ROW1)
  #undef ROW1
  float inv = (e1 > e0) ? 1.f/ssum : 0.f;
  bf16x8 rv = *(const bf16x8*)(resb + (size_t)n*CC + l*8);
  bf16x8 hb8;
  #pragma unroll
  for (int i=0;i<8;i++){
    float v = bf2f((unsigned short)rv[i]) + r[i]*inv;
    v = v > 0.f ? v : __expf(v)-1.f;
    hb8[i] = (short)f2bf(v);
  }
  *(bf16x8*)(hb + (size_t)n*CC + l*8) = hb8;
}

// ---- layer2 aggregation + readout + output: ONE BLOCK PER GRAPH,
//      16 lanes/node (8 ch/lane), graph sum/max in regs + LDS combine ----
__global__ __launch_bounds__(256) void k_aggr2(
    const int* __restrict__ gptr, const int* __restrict__ rowptr,
    const int* __restrict__ csr,
    const float* __restrict__ el, const float* __restrict__ er,
    const unsigned short* __restrict__ featb,
    const unsigned short* __restrict__ hb,
    const float* __restrict__ b2, const float* __restrict__ aww,
    const float* __restrict__ awb,
    const float* __restrict__ outw, const float* __restrict__ outb,
    float* __restrict__ out)
{
  __shared__ float lsum[16][32];
  __shared__ float lmax[16][32];
  __shared__ float gv[64];
  __shared__ float rr1[2], rr2[2];
  int g = blockIdx.x;
  int n0 = gptr[g], n1 = gptr[g+1];
  int t = threadIdx.x;
  int grp = t>>4, l = t&15, h = l>>2;
  float gs[8] = {0.f,0.f,0.f,0.f,0.f,0.f,0.f,0.f};
  float gm[8] = {-3.4e38f,-3.4e38f,-3.4e38f,-3.4e38f,-3.4e38f,-3.4e38f,-3.4e38f,-3.4e38f};
  float bvv[8], awv[8];
  #pragma unroll
  for (int i=0;i<8;i++){
    bvv[i] = b2[l*8+i];
    awv[i] = aww[(l&3)*8+i];
  }
  float awbv = awb[0];
  for (int n = n0+grp; n < n1; n += 16){
    int e0 = rowptr[n], e1 = rowptr[n+1];
    float ern = er[n*HH + h];
    float ssum = 0.f;
    float r[8] = {0.f,0.f,0.f,0.f,0.f,0.f,0.f,0.f};
    #define ROW2(s) (*(const bf16x8*)(featb + (size_t)(s)*CC + l*8))
    EDGE_LOOP(ROW2)
    #undef ROW2
    float inv = (e1 > e0) ? 1.f/ssum : 0.f;
    bf16x8 hv = *(const bf16x8*)(hb + (size_t)n*CC + l*8);
    float p = 0.f;
    float hm[8];
    #pragma unroll
    for (int i=0;i<8;i++){
      float v = bf2f((unsigned short)hv[i]) + bvv[i] + r[i]*inv;
      v += __shfl_xor(v, 4, 16);
      v += __shfl_xor(v, 8, 16);
      hm[i] = 0.25f*v;
      p = fmaf(hm[i], awv[i], p);
    }
    p += __shfl_xor(p, 1, 16);
    p += __shfl_xor(p, 2, 16);
    float wgt = 1.f/(1.f + __expf(-(p + awbv)));
    #pragma unroll
    for (int i=0;i<8;i++){
      gs[i] = fmaf(wgt, hm[i], gs[i]);
      gm[i] = fmaxf(gm[i], hm[i]);
    }
  }
  if (l < 4){
    #pragma unroll
    for (int i=0;i<8;i++){
      lsum[grp][l*8+i] = gs[i];
      lmax[grp][l*8+i] = gm[i];
    }
  }
  __syncthreads();
  if (t < 32){
    float s=0.f, m=-3.4e38f;
    #pragma unroll
    for (int q=0;q<16;q++){ s += lsum[q][t]; m = fmaxf(m, lmax[q][t]); }
    gv[t]    = s;
    gv[32+t] = (m < -3.0e38f) ? 0.f : m;
  }
  __syncthreads();
  float y = 0.f;
  if (t < 128){
    y = outb[t];
    #pragma unroll
    for (int jj=0;jj<64;jj++) y = fmaf(gv[jj], outw[t*64+jj], y);
    float s1 = y, s2 = y*y;
    #pragma unroll
    for (int o=32;o;o>>=1){ s1 += __shfl_xor(s1,o); s2 += __shfl_xor(s2,o); }
    if ((t&63)==0){ rr1[t>>6]=s1; rr2[t>>6]=s2; }
  }
  __syncthreads();
  if (t < 128){
    float S1 = rr1[0]+rr1[1], S2 = rr2[0]+rr2[1];
    float mu = S1*(1.f/128.f);
    float var = S2*(1.f/128.f) - mu*mu;
    out[g*CC + t] = (y - mu) * rsqrtf(var + 1e-5f);
  }
}

extern "C" void kernel_launch(void* const* d_in, const int* in_sizes, int n_in,
                              void* d_out, int out_size, void* d_ws, size_t ws_size,
                              hipStream_t stream){
  const float* x     = (const float*)d_in[0];
  const int*   src   = (const int*)d_in[1];
  const int*   dst   = (const int*)d_in[2];
  const int*   gid   = (const int*)d_in[3];
  const float* fc1w  = (const float*)d_in[4];
  const float* al1   = (const float*)d_in[5];
  const float* ar1   = (const float*)d_in[6];
  const float* res1w = (const float*)d_in[7];
  const float* b1    = (const float*)d_in[8];
  const float* fc2w  = (const float*)d_in[9];
  const float* al2   = (const float*)d_in[10];
  const float* ar2   = (const float*)d_in[11];
  const float* b2    = (const float*)d_in[12];
  const float* aww   = (const float*)d_in[13];
  const float* awb   = (const float*)d_in[14];
  const float* outw  = (const float*)d_in[15];
  const float* outb  = (const float*)d_in[16];
  float* out = (float*)d_out;

  char* w = (char*)d_ws;
  unsigned short* featb = (unsigned short*)w;  w += (size_t)NN*CC*2;   // 25.6MB
  unsigned short* hb    = (unsigned short*)w;  w += (size_t)NN*CC*2;   // 25.6MB
  unsigned short* resb  = (unsigned short*)w;  w += (size_t)NN*CC*2;   // 25.6MB
  float*          el    = (float*)w;           w += (size_t)NN*HH*4;
  float*          er    = (float*)w;           w += (size_t)NN*HH*4;
  int*            deg   = (int*)w;             w += (size_t)NN*4;
  int*            rowptr= (int*)w;             w += (size_t)(NN+1)*4;
  int*            cursor= (int*)w;             w += (size_t)NN*4;
  int*            bsum  = (int*)w;             w += 128*4;
  int*            csr   = (int*)w;             w += (size_t)EE*4;
  int*            gptr  = (int*)w;             w += (size_t)(GG+1)*4;
  unsigned short* wb2   = (unsigned short*)w;  w += (size_t)CC*CC*2;
  unsigned short* xb    = (unsigned short*)w;  w += (size_t)NN*32*2;   // 6.4MB
  unsigned short* wb1   = (unsigned short*)w;  w += (size_t)CC*32*2;
  unsigned short* wrb   = (unsigned short*)w;  w += (size_t)CC*32*2;

  const int EB = (EE + 255)/256;

  // fused prep (deg zero, gptr, bf16 converts) + CSR build
  k_prep<<<(NN*32+255)/256,256,0,stream>>>(x, fc1w, res1w, fc2w, gid,
                                           xb, wb1, wrb, wb2, deg, gptr);
  k_count<<<EB,256,0,stream>>>(dst, deg);
  k_scan_local<<<NB,256,0,stream>>>(deg, rowptr, bsum);
  k_scan_bsums<<<1,64,0,stream>>>(bsum, rowptr);
  k_scan_add<<<NB,256,0,stream>>>(rowptr, bsum, cursor);
  k_scatter<<<EB,256,0,stream>>>(src, dst, cursor, csr);

  // layer 1 (MFMA)
  k_feat1m<<<1024,256,0,stream>>>(xb, wb1, wrb, b1, al1, ar1, featb, resb, el, er);
  k_aggr1<<<(NN+15)/16,256,0,stream>>>(rowptr, csr, el, er, featb, resb, hb);
  // layer 2
  k_feat2<<<(NN/16*2+3)/4,256,0,stream>>>(hb, wb2, al2, ar2, featb, el, er);
  // fused aggregation + readout + gnn_last + LayerNorm (block per graph)
  k_aggr2<<<GG,256,0,stream>>>(gptr, rowptr, csr, el, er, featb, hb,
                               b2, aww, awb, outw, outb, out);
}